// Round 1
// baseline (1723.793 us; speedup 1.0000x reference)
//
#include <hip/hip_runtime.h>
#include <hip/hip_bf16.h>

#define CB 256       // batch
#define CS 200       // seq
#define CH 128       // H
#define CH2 256      // 2H
#define CLLM 768
#define CL 256       // padded length
#define CPAD 56
#define CBS (CB*CS)  // 51200 tokens
#define CBL (CB*CL)  // 65536 padded rows

// ---------------- static device buffers (capture-safe, no ws dependence) ---
__device__ float g_cat [(size_t)CBS*2*CH]; // [ids | llm] per token
__device__ float g_g1  [(size_t)CBS*2*CH]; // gelu(cat@Wg1^T+bg1)
__device__ float g_gate[(size_t)CBS*CH];
__device__ float g_x   [(size_t)CBL*CH];
__device__ float g_y   [(size_t)CBL*CH];
__device__ float g_hre [(size_t)CBL*CH2];
__device__ float g_him [(size_t)CBL*CH2];
__device__ float g_ffh [(size_t)CBL*4*CH];
__device__ float g_mask[CBL];
__device__ float g_gamma[CH2];
__device__ float g_lre[128*CH2];  // row k-1 = Re(lambda^k), k=1..128
__device__ float g_lim[128*CH2];

__device__ __forceinline__ float* buf_ptr(int s){
  switch(s){
    case 0: return g_cat; case 1: return g_g1; case 2: return g_gate;
    case 3: return g_x;   case 4: return g_y;  case 5: return g_hre;
    case 6: return g_him; case 7: return g_ffh; default: return nullptr;
  }
}

__device__ __forceinline__ float wave_sum(float v){
  #pragma unroll
  for (int off = 32; off; off >>= 1) v += __shfl_xor(v, off);
  return v;
}

// ---------------- mask ------------------------------------------------------
__global__ void k_mask(const int* __restrict__ ids){
  int b = blockIdx.x, t = threadIdx.x;
  float m = 0.f;
  if (t >= CPAD) m = (ids[b*CS + (t - CPAD)] > 0) ? 1.f : 0.f;
  g_mask[b*CL + t] = m;
}

// ---------------- item-embedding gather into cat[:, :128] -------------------
__global__ void k_gather_ids(const int* __restrict__ ids,
                             const float* __restrict__ item_emb){
  int tok = blockIdx.x, c = threadIdx.x;
  int id = ids[tok];
  g_cat[(size_t)tok*2*CH + c] = item_emb[(size_t)id*CH + c];
}

// ---------------- generic tiled SGEMM: C = act((A@W^T [- A2@W2^T]) + bias) --
// A: M x K (row-major, stride lda), W: N x K (row-major, stride K)
// tile 64x64, BK=16, 256 threads, 4x4 per thread.
template<int ACT, bool DUAL, bool GATHER, bool COLSCALE>
__global__ __launch_bounds__(256) void k_gemm(
    int aSel, const float* __restrict__ Aext,
    const float* __restrict__ W1,
    int a2Sel, const float* __restrict__ W2,
    const float* __restrict__ bias,
    const int* __restrict__ gidx,
    int cSel, long cOff,
    int K, int lda, int ldc)
{
  __shared__ float As1[16][64], Ws1[16][64];
  __shared__ float As2[DUAL?16:1][64], Ws2[DUAL?16:1][64];

  const float* A1 = (aSel >= 0) ? buf_ptr(aSel) : Aext;
  const float* A2 = DUAL ? buf_ptr(a2Sel) : nullptr;
  float* C = buf_ptr(cSel) + cOff;

  int tid = threadIdx.x;
  int tx = tid & 15, ty = tid >> 4;
  int tx4 = tx*4, ty4 = ty*4;
  int m0 = blockIdx.x * 64, n0 = blockIdx.y * 64;
  int lr = tid >> 2;          // 0..63
  int kq = (tid & 3) * 4;     // 0,4,8,12

  long arow = m0 + lr;
  if (GATHER) arow = gidx[m0 + lr];
  const float* a1p = A1 + arow*(long)lda + kq;
  const float* w1p = W1 + (long)(n0 + lr)*K + kq;
  const float* a2p = DUAL ? (A2 + (long)(m0 + lr)*lda + kq) : nullptr;
  const float* w2p = DUAL ? (W2 + (long)(n0 + lr)*K + kq) : nullptr;

  float acc[4][4] = {};

  for (int k0 = 0; k0 < K; k0 += 16){
    float4 av = *(const float4*)(a1p + k0);
    float4 wv = *(const float4*)(w1p + k0);
    As1[kq+0][lr] = av.x; As1[kq+1][lr] = av.y; As1[kq+2][lr] = av.z; As1[kq+3][lr] = av.w;
    Ws1[kq+0][lr] = wv.x; Ws1[kq+1][lr] = wv.y; Ws1[kq+2][lr] = wv.z; Ws1[kq+3][lr] = wv.w;
    if (DUAL){
      float4 av2 = *(const float4*)(a2p + k0);
      float4 wv2 = *(const float4*)(w2p + k0);
      As2[kq+0][lr] = av2.x; As2[kq+1][lr] = av2.y; As2[kq+2][lr] = av2.z; As2[kq+3][lr] = av2.w;
      Ws2[kq+0][lr] = wv2.x; Ws2[kq+1][lr] = wv2.y; Ws2[kq+2][lr] = wv2.z; Ws2[kq+3][lr] = wv2.w;
    }
    __syncthreads();
    #pragma unroll
    for (int kk = 0; kk < 16; kk++){
      float4 a = *(const float4*)&As1[kk][ty4];
      float4 w = *(const float4*)&Ws1[kk][tx4];
      float ar[4] = {a.x,a.y,a.z,a.w};
      float wr[4] = {w.x,w.y,w.z,w.w};
      #pragma unroll
      for (int i=0;i<4;i++)
        #pragma unroll
        for (int j=0;j<4;j++)
          acc[i][j] = fmaf(ar[i], wr[j], acc[i][j]);
      if (DUAL){
        float4 a2 = *(const float4*)&As2[kk][ty4];
        float4 w2 = *(const float4*)&Ws2[kk][tx4];
        float ar2[4] = {a2.x,a2.y,a2.z,a2.w};
        float wr2[4] = {w2.x,w2.y,w2.z,w2.w};
        #pragma unroll
        for (int i=0;i<4;i++)
          #pragma unroll
          for (int j=0;j<4;j++)
            acc[i][j] = fmaf(-ar2[i], wr2[j], acc[i][j]);
      }
    }
    __syncthreads();
  }

  #pragma unroll
  for (int i=0;i<4;i++){
    long row = m0 + ty4 + i;
    float4 o;
    float vv[4];
    #pragma unroll
    for (int j=0;j<4;j++){
      int col = n0 + tx4 + j;
      float v = acc[i][j] + bias[col];
      if (COLSCALE) v *= g_gamma[col];
      if (ACT == 1) v = 0.5f * v * (1.0f + erff(v * 0.70710678118654752f)); // exact GELU
      else if (ACT == 2) v = 1.0f / (1.0f + expf(-v));                      // sigmoid
      vv[j] = v;
    }
    o.x = vv[0]; o.y = vv[1]; o.z = vv[2]; o.w = vv[3];
    *(float4*)(C + row*ldc + n0 + tx4) = o;
  }
}

// ---------------- zero the left-pad rows of x -------------------------------
__global__ void k_zero_pad(){
  int i = blockIdx.x*256 + threadIdx.x;   // over CB*CPAD*CH
  int c = i & (CH-1);
  int r = (i >> 7) % CPAD;
  int b = i / (CPAD*CH);
  g_x[((size_t)b*CL + r)*CH + c] = 0.f;
}

// ---------------- gated mix + LN0 -> x[b, PAD+s, :] -------------------------
__global__ __launch_bounds__(256) void k_mix_ln0(const float* __restrict__ g0,
                                                 const float* __restrict__ b0){
  int wave = threadIdx.x >> 6, lane = threadIdx.x & 63;
  long tok = (long)blockIdx.x*4 + wave;
  int b = (int)(tok / CS), s = (int)(tok - (long)b*CS);
  const float* cp = g_cat  + tok*2*CH;
  const float* gp = g_gate + tok*CH;
  int c0 = lane*2;
  float2 vid = *(const float2*)(cp + c0);
  float2 vlm = *(const float2*)(cp + CH + c0);
  float2 gg  = *(const float2*)(gp + c0);
  float v0 = gg.x*vid.x + (1.f-gg.x)*vlm.x;
  float v1 = gg.y*vid.y + (1.f-gg.y)*vlm.y;
  float mu = wave_sum(v0 + v1) * (1.f/128.f);
  float d0 = v0-mu, d1 = v1-mu;
  float var = wave_sum(d0*d0 + d1*d1) * (1.f/128.f);
  float rstd = rsqrtf(var + 1e-12f);
  float2 o;
  o.x = d0*rstd*g0[c0]   + b0[c0];
  o.y = d1*rstd*g0[c0+1] + b0[c0+1];
  float* xp = g_x + ((size_t)b*CL + CPAD + s)*CH;
  *(float2*)(xp + c0) = o;
}

// ---------------- per-layer prep: gamma + lambda power table ----------------
__global__ void k_prep(const float* __restrict__ params_log, int l){
  int d = threadIdx.x; // 256
  float nu = expf(params_log[(l*3+0)*CH2 + d]);
  float th = expf(params_log[(l*3+1)*CH2 + d]);
  g_gamma[d] = expf(params_log[(l*3+2)*CH2 + d]);
  float r = expf(-nu);
  float lre = r*cosf(th), limv = r*sinf(th);
  float pr = lre, pi = limv;
  for (int k = 0; k < 128; k++){
    g_lre[k*CH2 + d] = pr; g_lim[k*CH2 + d] = pi;
    float nr = pr*lre - pi*limv;
    float ni = pr*limv + pi*lre;
    pr = nr; pi = ni;
  }
}

// ---------------- blocked LRU scan (exact reference semantics) --------------
// block handles (b, 32 channels, all 256 t) in LDS; 8 levels.
__global__ __launch_bounds__(256) void k_scan(){
  __shared__ float sre[CL*32];
  __shared__ float sim[CL*32];
  int b = blockIdx.y, d0 = blockIdx.x*32;
  int tid = threadIdx.x;

  for (int idx = tid; idx < CL*32; idx += 256){
    int t = idx >> 5, dl = idx & 31;
    size_t g = ((size_t)(b*CL + t))*CH2 + d0 + dl;
    sre[idx] = g_hre[g];
    sim[idx] = g_him[g];
  }
  __syncthreads();

  for (int i = 1; i <= 8; i++){
    int half = 1 << (i-1);
    for (int w = tid; w < 128*32; w += 256){
      int dl = w & 31, u = w >> 5;         // u in 0..127
      int blk = u >> (i-1), j = u & (half-1);
      int p = (blk << i) + half - 1;       // boundary position
      int t = p + 1 + j;                   // target in second half
      float mv = g_mask[b*CL + p];
      float lr = g_lre[j*CH2 + d0 + dl];   // lambda^{j+1}
      float li = g_lim[j*CH2 + d0 + dl];
      float hr = sre[p*32 + dl], hi = sim[p*32 + dl];
      sre[t*32 + dl] += (lr*hr - li*hi) * mv;
      sim[t*32 + dl] += (lr*hi + li*hr) * mv;
    }
    __syncthreads();
  }

  for (int idx = tid; idx < CL*32; idx += 256){
    int t = idx >> 5, dl = idx & 31;
    size_t g = ((size_t)(b*CL + t))*CH2 + d0 + dl;
    g_hre[g] = sre[idx];
    g_him[g] = sim[idx];
  }
}

// ---------------- x = LN(y + x) --------------------------------------------
__global__ __launch_bounds__(256) void k_add_ln(const float* __restrict__ gam,
                                                const float* __restrict__ bet){
  int wave = threadIdx.x >> 6, lane = threadIdx.x & 63;
  long row = (long)blockIdx.x*4 + wave;
  const float* yp = g_y + row*CH;
  float* xp = g_x + row*CH;
  int c0 = lane*2;
  float2 a = *(const float2*)(yp + c0);
  float2 bb = *(const float2*)(xp + c0);
  float v0 = a.x + bb.x, v1 = a.y + bb.y;
  float mu = wave_sum(v0 + v1) * (1.f/128.f);
  float d0 = v0-mu, d1 = v1-mu;
  float var = wave_sum(d0*d0 + d1*d1) * (1.f/128.f);
  float rstd = rsqrtf(var + 1e-12f);
  float2 o;
  o.x = d0*rstd*gam[c0]   + bet[c0];
  o.y = d1*rstd*gam[c0+1] + bet[c0+1];
  *(float2*)(xp + c0) = o;
}

// ---------------- final copy: out = x[:, -S:] -------------------------------
__global__ void k_copy_out(float* __restrict__ out){
  int i = blockIdx.x*256 + threadIdx.x;  // over CBS*CH
  int tok = i >> 7, c = i & (CH-1);
  int b = tok / CS, s = tok - b*CS;
  out[i] = g_x[((size_t)b*CL + CPAD + s)*CH + c];
}

// ---------------------------------------------------------------------------
extern "C" void kernel_launch(void* const* d_in, const int* in_sizes, int n_in,
                              void* d_out, int out_size, void* d_ws, size_t ws_size,
                              hipStream_t stream) {
  const int*   ids       = (const int*)  d_in[0];
  const float* item_emb  = (const float*)d_in[1];
  const float* llm_emb   = (const float*)d_in[2];
  const float* W_map     = (const float*)d_in[3];
  const float* b_map     = (const float*)d_in[4];
  const float* Wg1       = (const float*)d_in[5];
  const float* bg1       = (const float*)d_in[6];
  const float* Wg2       = (const float*)d_in[7];
  const float* bg2       = (const float*)d_in[8];
  const float* ln0_g     = (const float*)d_in[9];
  const float* ln0_b     = (const float*)d_in[10];
  const float* params_log= (const float*)d_in[11];
  const float* Win_re    = (const float*)d_in[12];
  const float* Win_im    = (const float*)d_in[13];
  const float* bin_re    = (const float*)d_in[14];
  const float* bin_im    = (const float*)d_in[15];
  const float* Wout_re   = (const float*)d_in[16];
  const float* Wout_im   = (const float*)d_in[17];
  const float* bout_re   = (const float*)d_in[18];
  const float* ln1_g     = (const float*)d_in[20];
  const float* ln1_b     = (const float*)d_in[21];
  const float* Wff1      = (const float*)d_in[22];
  const float* bff1      = (const float*)d_in[23];
  const float* Wff2      = (const float*)d_in[24];
  const float* bff2      = (const float*)d_in[25];
  const float* ln2_g     = (const float*)d_in[26];
  const float* ln2_b     = (const float*)d_in[27];
  float* out = (float*)d_out;

  dim3 blk(256);

  k_mask<<<CB, CL, 0, stream>>>(ids);
  k_gather_ids<<<CBS, CH, 0, stream>>>(ids, item_emb);

  // llm = llm_emb[ids] @ W_map^T + b_map  -> cat[:,128:256]
  k_gemm<0,false,true ,false><<<dim3(CBS/64, CH/64), blk, 0, stream>>>(
      -1, llm_emb, W_map, -1, nullptr, b_map, ids, 0, 128, CLLM, CLLM, 2*CH);
  // g1 = gelu(cat @ Wg1^T + bg1)
  k_gemm<1,false,false,false><<<dim3(CBS/64, 2*CH/64), blk, 0, stream>>>(
      0, nullptr, Wg1, -1, nullptr, bg1, nullptr, 1, 0, 2*CH, 2*CH, 2*CH);
  // gate = sigmoid(g1 @ Wg2^T + bg2)
  k_gemm<2,false,false,false><<<dim3(CBS/64, CH/64), blk, 0, stream>>>(
      1, nullptr, Wg2, -1, nullptr, bg2, nullptr, 2, 0, 2*CH, 2*CH, CH);

  k_zero_pad<<<(CB*CPAD*CH)/256, blk, 0, stream>>>();
  k_mix_ln0<<<CBS/4, blk, 0, stream>>>(ln0_g, ln0_b);

  for (int l = 0; l < 2; l++){
    k_prep<<<1, CH2, 0, stream>>>(params_log, l);
    // h_re = (x @ Win_re^T + bin_re) * gamma ; h_im likewise
    k_gemm<0,false,false,true ><<<dim3(CBL/64, CH2/64), blk, 0, stream>>>(
        3, nullptr, Win_re + (size_t)l*CH2*CH, -1, nullptr, bin_re + l*CH2,
        nullptr, 5, 0, CH, CH, CH2);
    k_gemm<0,false,false,true ><<<dim3(CBL/64, CH2/64), blk, 0, stream>>>(
        3, nullptr, Win_im + (size_t)l*CH2*CH, -1, nullptr, bin_im + l*CH2,
        nullptr, 6, 0, CH, CH, CH2);

    k_scan<<<dim3(CH2/32, CB), blk, 0, stream>>>();

    // y = h_re @ Wout_re^T - h_im @ Wout_im^T + bout_re
    k_gemm<0,true ,false,false><<<dim3(CBL/64, CH/64), blk, 0, stream>>>(
        5, nullptr, Wout_re + (size_t)l*CH*CH2, 6, Wout_im + (size_t)l*CH*CH2,
        bout_re + l*CH, nullptr, 4, 0, CH2, CH2, CH);
    k_add_ln<<<CBL/4, blk, 0, stream>>>(ln1_g + l*CH, ln1_b + l*CH);

    // ffh = gelu(x @ Wff1^T + bff1)
    k_gemm<1,false,false,false><<<dim3(CBL/64, 4*CH/64), blk, 0, stream>>>(
        3, nullptr, Wff1 + (size_t)l*4*CH*CH, -1, nullptr, bff1 + l*4*CH,
        nullptr, 7, 0, CH, CH, 4*CH);
    // y = ffh @ Wff2^T + bff2
    k_gemm<0,false,false,false><<<dim3(CBL/64, CH/64), blk, 0, stream>>>(
        7, nullptr, Wff2 + (size_t)l*CH*4*CH, -1, nullptr, bff2 + l*CH,
        nullptr, 4, 0, 4*CH, 4*CH, CH);
    k_add_ln<<<CBL/4, blk, 0, stream>>>(ln2_g + l*CH, ln2_b + l*CH);
  }

  k_copy_out<<<(CBS*CH)/256, blk, 0, stream>>>(out);
}

// Round 2
// 715.582 us; speedup vs baseline: 2.4089x; 2.4089x over previous
//
#include <hip/hip_runtime.h>
#include <hip/hip_bf16.h>

#define CB 256       // batch
#define CS 200       // seq
#define CH 128       // H
#define CH2 256      // 2H
#define CL 256       // padded length
#define CPAD 56
#define CBS (CB*CS)  // 51200 tokens
#define CBL (CB*CL)  // 65536 padded rows

typedef __attribute__((ext_vector_type(8))) short bf16x8;
typedef __attribute__((ext_vector_type(4))) float f32x4;

// ---------------- static device buffers ------------------------------------
__device__ __hip_bfloat16 g_cat [(size_t)CBS*256]; // [ids | llm] bf16
__device__ __hip_bfloat16 g_g1  [(size_t)CBS*256];
__device__ __hip_bfloat16 g_gate[(size_t)CBS*128];
__device__ float          g_x   [(size_t)CBL*128]; // residual stream f32
__device__ __hip_bfloat16 g_xb  [(size_t)CBL*128]; // bf16 copy of x (GEMM A)
__device__ __hip_bfloat16 g_y   [(size_t)CBL*128];
__device__ __hip_bfloat16 g_h   [(size_t)CBL*512]; // [re | im]
__device__ __hip_bfloat16 g_ffh [(size_t)CBL*512];
__device__ float g_mask[CBL];
__device__ float g_gamma2[512];
__device__ float g_bincat[512];
__device__ float g_lre[128*CH2];
__device__ float g_lim[128*CH2];
// bf16 weight copies
__device__ __hip_bfloat16 g_Wmap  [128*768];
__device__ __hip_bfloat16 g_Wg1   [256*256];
__device__ __hip_bfloat16 g_Wg2   [128*256];
__device__ __hip_bfloat16 g_Wincat[512*128];
__device__ __hip_bfloat16 g_Woutcat[128*512];
__device__ __hip_bfloat16 g_Wff1  [512*128];
__device__ __hip_bfloat16 g_Wff2  [128*512];

__device__ __forceinline__ __hip_bfloat16* bbuf(int s){
  switch(s){
    case 0: return g_cat;   case 1: return g_g1;    case 2: return g_gate;
    case 3: return g_xb;    case 4: return g_y;     case 5: return g_h;
    case 6: return g_ffh;   case 7: return g_Wmap;  case 8: return g_Wg1;
    case 9: return g_Wg2;   case 10: return g_Wincat; case 11: return g_Woutcat;
    case 12: return g_Wff1; case 13: return g_Wff2; default: return nullptr;
  }
}

__device__ __forceinline__ short f2bf(float f){
  unsigned u = __float_as_uint(f);
  unsigned r = (u + 0x7fffu + ((u>>16)&1u)) >> 16;
  return (short)r;
}
__device__ __forceinline__ float bf2f(short s){
  return __uint_as_float(((unsigned)(unsigned short)s) << 16);
}
__device__ __forceinline__ float wave_sum(float v){
  #pragma unroll
  for (int off = 32; off; off >>= 1) v += __shfl_xor(v, off);
  return v;
}

// ---------------- mask ------------------------------------------------------
__global__ void k_mask(const int* __restrict__ ids){
  int b = blockIdx.x, t = threadIdx.x;
  float m = 0.f;
  if (t >= CPAD) m = (ids[b*CS + (t - CPAD)] > 0) ? 1.f : 0.f;
  g_mask[b*CL + t] = m;
}

// ---------------- item-embedding gather into cat[:, :128] (bf16) -----------
__global__ void k_gather_ids(const int* __restrict__ ids,
                             const float* __restrict__ item_emb){
  int tok = blockIdx.x, c = threadIdx.x;
  int id = ids[tok];
  g_cat[(size_t)tok*256 + c] = __float2bfloat16(item_emb[(size_t)id*128 + c]);
}

// ---------------- weight converts ------------------------------------------
__global__ void k_wcvt(const float* __restrict__ s, int dSel, long dOff, int n){
  int i = blockIdx.x*256 + threadIdx.x;
  if (i < n) bbuf(dSel)[dOff + i] = __float2bfloat16(s[i]);
}
__global__ void k_wcat_out(const float* __restrict__ wre,
                           const float* __restrict__ wim){
  int i = blockIdx.x*256 + threadIdx.x;  // 128*512
  int r = i >> 9, c = i & 511;
  float v = (c < 256) ? wre[r*256 + c] : -wim[r*256 + (c - 256)];
  g_Woutcat[i] = __float2bfloat16(v);
}

// ---------------- MFMA GEMM: C = act((A@W^T)+bias [*gamma]) ----------------
// A: M x lda bf16 (or f32 gathered), W: N x K bf16 row-major, C bf16.
// tile 128x128, BK=32, 4 waves (2x2), 4x4 16x16 fragments per wave.
template<int ACT, bool GATHER, bool COLSCALE>
__global__ __launch_bounds__(256) void k_mgemm(
    int aSel, const float* __restrict__ Af32,
    int wSel, int biasSel, const float* __restrict__ biasExt,
    const int* __restrict__ gidx,
    int cSel, long cOff, int ldc, int K, int lda)
{
  __shared__ char lA[128*80];
  __shared__ char lB[128*80];
  const short* A = GATHER ? nullptr : (const short*)bbuf(aSel);
  const short* W = (const short*)bbuf(wSel);
  const float* bias = (biasSel == 0) ? g_bincat : biasExt;
  __hip_bfloat16* C = bbuf(cSel) + cOff;

  const int t = threadIdx.x;
  const int m0 = blockIdx.x*128, n0 = blockIdx.y*128;
  const int lane = t & 63, wv = t >> 6;
  const int wr = wv >> 1, wc = wv & 1;
  const int fr = lane & 15, fq = lane >> 4;
  const int srow = t >> 2, sq = t & 3;      // staging: row, 8-elem quarter

  f32x4 acc[4][4] = {};

  for (int k0 = 0; k0 < K; k0 += 32){
    #pragma unroll
    for (int i = 0; i < 2; i++){
      int row = srow + i*64;
      bf16x8 av;
      if (GATHER){
        long ar = gidx[m0 + row];
        const float* p = Af32 + ar*(long)lda + k0 + sq*8;
        float4 x0 = *(const float4*)p;
        float4 x1 = *(const float4*)(p + 4);
        av[0]=f2bf(x0.x); av[1]=f2bf(x0.y); av[2]=f2bf(x0.z); av[3]=f2bf(x0.w);
        av[4]=f2bf(x1.x); av[5]=f2bf(x1.y); av[6]=f2bf(x1.z); av[7]=f2bf(x1.w);
      } else {
        av = *(const bf16x8*)(A + (long)(m0+row)*lda + k0 + sq*8);
      }
      *(bf16x8*)(lA + row*80 + sq*16) = av;
      bf16x8 wv8 = *(const bf16x8*)(W + (long)(n0+row)*K + k0 + sq*8);
      *(bf16x8*)(lB + row*80 + sq*16) = wv8;
    }
    __syncthreads();
    bf16x8 af[4], bw[4];
    #pragma unroll
    for (int m = 0; m < 4; m++)
      af[m] = *(const bf16x8*)(lA + (wr*64 + m*16 + fr)*80 + fq*16);
    #pragma unroll
    for (int n = 0; n < 4; n++)
      bw[n] = *(const bf16x8*)(lB + (wc*64 + n*16 + fr)*80 + fq*16);
    #pragma unroll
    for (int m = 0; m < 4; m++)
      #pragma unroll
      for (int n = 0; n < 4; n++)
        acc[m][n] = __builtin_amdgcn_mfma_f32_16x16x32_bf16(af[m], bw[n], acc[m][n], 0, 0, 0);
    __syncthreads();
  }

  #pragma unroll
  for (int m = 0; m < 4; m++){
    #pragma unroll
    for (int j = 0; j < 4; j++){
      long row = m0 + wr*64 + m*16 + fq*4 + j;
      __hip_bfloat16* cp = C + row*(long)ldc;
      #pragma unroll
      for (int n = 0; n < 4; n++){
        int col = n0 + wc*64 + n*16 + fr;
        float v = acc[m][n][j] + bias[col];
        if (COLSCALE) v *= g_gamma2[col];
        if (ACT == 1) v = 0.5f * v * (1.0f + erff(v * 0.70710678118654752f));
        else if (ACT == 2) v = 1.0f / (1.0f + expf(-v));
        cp[col] = __float2bfloat16(v);
      }
    }
  }
}

// ---------------- zero pad rows of x ----------------------------------------
__global__ void k_zero_pad(){
  int i = blockIdx.x*256 + threadIdx.x;   // over CB*CPAD*CH
  int c = i & (CH-1);
  int r = (i >> 7) % CPAD;
  int b = i / (CPAD*CH);
  size_t o = ((size_t)b*CL + r)*CH + c;
  g_x[o] = 0.f;
  g_xb[o] = __float2bfloat16(0.f);
}

// ---------------- gated mix + LN0 ------------------------------------------
__global__ __launch_bounds__(256) void k_mix_ln0(const float* __restrict__ g0,
                                                 const float* __restrict__ b0){
  int wavei = threadIdx.x >> 6, lane = threadIdx.x & 63;
  long tok = (long)blockIdx.x*4 + wavei;
  int b = (int)(tok / CS), s = (int)(tok - (long)b*CS);
  const __hip_bfloat16* cp = g_cat  + tok*256;
  const __hip_bfloat16* gp = g_gate + tok*128;
  int c0 = lane*2;
  float i0 = __bfloat162float(cp[c0]),     i1 = __bfloat162float(cp[c0+1]);
  float l0 = __bfloat162float(cp[128+c0]), l1 = __bfloat162float(cp[128+c0+1]);
  float gg0 = __bfloat162float(gp[c0]),    gg1 = __bfloat162float(gp[c0+1]);
  float v0 = gg0*i0 + (1.f-gg0)*l0;
  float v1 = gg1*i1 + (1.f-gg1)*l1;
  float mu = wave_sum(v0 + v1) * (1.f/128.f);
  float d0 = v0-mu, d1 = v1-mu;
  float var = wave_sum(d0*d0 + d1*d1) * (1.f/128.f);
  float rstd = rsqrtf(var + 1e-12f);
  float o0 = d0*rstd*g0[c0]   + b0[c0];
  float o1 = d1*rstd*g0[c0+1] + b0[c0+1];
  size_t ro = ((size_t)b*CL + CPAD + s)*128;
  g_x [ro+c0] = o0; g_x [ro+c0+1] = o1;
  g_xb[ro+c0] = __float2bfloat16(o0); g_xb[ro+c0+1] = __float2bfloat16(o1);
}

// ---------------- per-layer prep -------------------------------------------
__global__ void k_prep(const float* __restrict__ pl,
                       const float* __restrict__ binre,
                       const float* __restrict__ binim, int l){
  int d = threadIdx.x; // 256
  float nu = expf(pl[(l*3+0)*CH2 + d]);
  float th = expf(pl[(l*3+1)*CH2 + d]);
  float gm = expf(pl[(l*3+2)*CH2 + d]);
  g_gamma2[d] = gm; g_gamma2[d+256] = gm;
  g_bincat[d] = binre[d]; g_bincat[d+256] = binim[d];
  float r = expf(-nu);
  float lre = r*cosf(th), limv = r*sinf(th);
  float pr = lre, pi = limv;
  for (int k = 0; k < 128; k++){
    g_lre[k*CH2 + d] = pr; g_lim[k*CH2 + d] = pi;
    float nr = pr*lre - pi*limv;
    float ni = pr*limv + pi*lre;
    pr = nr; pi = ni;
  }
}

// ---------------- blocked LRU scan (exact reference semantics) --------------
__global__ __launch_bounds__(256) void k_scan(){
  __shared__ float sre[CL*32];
  __shared__ float sim[CL*32];
  int b = blockIdx.y, d0 = blockIdx.x*32;
  int tid = threadIdx.x;
  const short* H = (const short*)g_h;

  for (int idx = tid; idx < CL*8; idx += 256){
    int t = idx >> 3, dg = (idx & 7)*4;
    size_t base = ((size_t)(b*CL + t))*512 + d0 + dg;
    short4 r4 = *(const short4*)(H + base);
    short4 i4 = *(const short4*)(H + base + 256);
    int li = t*32 + dg;
    sre[li+0]=bf2f(r4.x); sre[li+1]=bf2f(r4.y); sre[li+2]=bf2f(r4.z); sre[li+3]=bf2f(r4.w);
    sim[li+0]=bf2f(i4.x); sim[li+1]=bf2f(i4.y); sim[li+2]=bf2f(i4.z); sim[li+3]=bf2f(i4.w);
  }
  __syncthreads();

  for (int i = 1; i <= 8; i++){
    int half = 1 << (i-1);
    for (int w = tid; w < 128*32; w += 256){
      int dl = w & 31, u = w >> 5;
      int blk = u >> (i-1), j = u & (half-1);
      int p = (blk << i) + half - 1;
      int tt = p + 1 + j;
      float mv = g_mask[b*CL + p];
      float lr = g_lre[j*CH2 + d0 + dl];
      float li = g_lim[j*CH2 + d0 + dl];
      float hr = sre[p*32 + dl], hi = sim[p*32 + dl];
      sre[tt*32 + dl] += (lr*hr - li*hi) * mv;
      sim[tt*32 + dl] += (lr*hi + li*hr) * mv;
    }
    __syncthreads();
  }

  short* Ho = (short*)g_h;
  for (int idx = tid; idx < CL*8; idx += 256){
    int t = idx >> 3, dg = (idx & 7)*4;
    size_t base = ((size_t)(b*CL + t))*512 + d0 + dg;
    int li = t*32 + dg;
    short4 r4, i4;
    r4.x=f2bf(sre[li+0]); r4.y=f2bf(sre[li+1]); r4.z=f2bf(sre[li+2]); r4.w=f2bf(sre[li+3]);
    i4.x=f2bf(sim[li+0]); i4.y=f2bf(sim[li+1]); i4.z=f2bf(sim[li+2]); i4.w=f2bf(sim[li+3]);
    *(short4*)(Ho + base) = r4;
    *(short4*)(Ho + base + 256) = i4;
  }
}

// ---------------- x = LN(y + x) --------------------------------------------
__global__ __launch_bounds__(256) void k_add_ln(const float* __restrict__ gam,
                                                const float* __restrict__ bet){
  int wavei = threadIdx.x >> 6, lane = threadIdx.x & 63;
  long row = (long)blockIdx.x*4 + wavei;
  const __hip_bfloat16* yp = g_y + row*128;
  float* xp = g_x + row*128;
  int c0 = lane*2;
  float v0 = __bfloat162float(yp[c0])   + xp[c0];
  float v1 = __bfloat162float(yp[c0+1]) + xp[c0+1];
  float mu = wave_sum(v0 + v1) * (1.f/128.f);
  float d0 = v0-mu, d1 = v1-mu;
  float var = wave_sum(d0*d0 + d1*d1) * (1.f/128.f);
  float rstd = rsqrtf(var + 1e-12f);
  float o0 = d0*rstd*gam[c0]   + bet[c0];
  float o1 = d1*rstd*gam[c0+1] + bet[c0+1];
  xp[c0] = o0; xp[c0+1] = o1;
  __hip_bfloat16* xbp = g_xb + row*128;
  xbp[c0] = __float2bfloat16(o0); xbp[c0+1] = __float2bfloat16(o1);
}

// ---------------- final copy -----------------------------------------------
__global__ void k_copy_out(float* __restrict__ out){
  int i = blockIdx.x*256 + threadIdx.x;  // over CBS*CH
  int tok = i >> 7, c = i & (CH-1);
  int b = tok / CS, s = tok - b*CS;
  out[i] = g_x[((size_t)b*CL + CPAD + s)*CH + c];
}

// ---------------------------------------------------------------------------
extern "C" void kernel_launch(void* const* d_in, const int* in_sizes, int n_in,
                              void* d_out, int out_size, void* d_ws, size_t ws_size,
                              hipStream_t stream) {
  const int*   ids       = (const int*)  d_in[0];
  const float* item_emb  = (const float*)d_in[1];
  const float* llm_emb   = (const float*)d_in[2];
  const float* W_map     = (const float*)d_in[3];
  const float* b_map     = (const float*)d_in[4];
  const float* Wg1       = (const float*)d_in[5];
  const float* bg1       = (const float*)d_in[6];
  const float* Wg2       = (const float*)d_in[7];
  const float* bg2       = (const float*)d_in[8];
  const float* ln0_g     = (const float*)d_in[9];
  const float* ln0_b     = (const float*)d_in[10];
  const float* params_log= (const float*)d_in[11];
  const float* Win_re    = (const float*)d_in[12];
  const float* Win_im    = (const float*)d_in[13];
  const float* bin_re    = (const float*)d_in[14];
  const float* bin_im    = (const float*)d_in[15];
  const float* Wout_re   = (const float*)d_in[16];
  const float* Wout_im   = (const float*)d_in[17];
  const float* bout_re   = (const float*)d_in[18];
  const float* ln1_g     = (const float*)d_in[20];
  const float* ln1_b     = (const float*)d_in[21];
  const float* Wff1      = (const float*)d_in[22];
  const float* bff1      = (const float*)d_in[23];
  const float* Wff2      = (const float*)d_in[24];
  const float* bff2      = (const float*)d_in[25];
  const float* ln2_g     = (const float*)d_in[26];
  const float* ln2_b     = (const float*)d_in[27];
  float* out = (float*)d_out;

  dim3 blk(256);

  // front-end weight converts
  k_wcvt<<<384, blk, 0, stream>>>(W_map, 7, 0, 128*768);
  k_wcvt<<<256, blk, 0, stream>>>(Wg1,   8, 0, 256*256);
  k_wcvt<<<128, blk, 0, stream>>>(Wg2,   9, 0, 128*256);

  k_mask<<<CB, CL, 0, stream>>>(ids);
  k_gather_ids<<<CBS, CH, 0, stream>>>(ids, item_emb);

  // llm = llm_emb[ids] @ W_map^T + b_map -> cat[:,128:256]
  k_mgemm<0,true ,false><<<dim3(400,1), blk, 0, stream>>>(
      -1, llm_emb, 7, -1, b_map, ids, 0, 128, 256, 768, 768);
  // g1 = gelu(cat @ Wg1^T + bg1)
  k_mgemm<1,false,false><<<dim3(400,2), blk, 0, stream>>>(
      0, nullptr, 8, -1, bg1, nullptr, 1, 0, 256, 256, 256);
  // gate = sigmoid(g1 @ Wg2^T + bg2)
  k_mgemm<2,false,false><<<dim3(400,1), blk, 0, stream>>>(
      1, nullptr, 9, -1, bg2, nullptr, 2, 0, 128, 256, 256);

  k_zero_pad<<<(CB*CPAD*CH)/256, blk, 0, stream>>>();
  k_mix_ln0<<<CBS/4, blk, 0, stream>>>(ln0_g, ln0_b);

  for (int l = 0; l < 2; l++){
    k_prep<<<1, CH2, 0, stream>>>(params_log, bin_re + l*256, bin_im + l*256, l);
    k_wcvt<<<128, blk, 0, stream>>>(Win_re + (size_t)l*32768, 10, 0,     32768);
    k_wcvt<<<128, blk, 0, stream>>>(Win_im + (size_t)l*32768, 10, 32768, 32768);
    k_wcat_out<<<256, blk, 0, stream>>>(Wout_re + (size_t)l*32768, Wout_im + (size_t)l*32768);
    k_wcvt<<<256, blk, 0, stream>>>(Wff1 + (size_t)l*65536, 12, 0, 65536);
    k_wcvt<<<256, blk, 0, stream>>>(Wff2 + (size_t)l*65536, 13, 0, 65536);

    // h_cat = (x @ Win_cat^T + bin_cat) * gamma_cat
    k_mgemm<0,false,true ><<<dim3(512,4), blk, 0, stream>>>(
        3, nullptr, 10, 0, nullptr, nullptr, 5, 0, 512, 128, 128);

    k_scan<<<dim3(CH2/32, CB), blk, 0, stream>>>();

    // y = h_cat @ Wout_cat^T + bout_re   (Wout_cat im half pre-negated)
    k_mgemm<0,false,false><<<dim3(512,1), blk, 0, stream>>>(
        5, nullptr, 11, -1, bout_re + l*128, nullptr, 4, 0, 128, 512, 512);
    k_add_ln<<<CBL/4, blk, 0, stream>>>(ln1_g + l*128, ln1_b + l*128);

    // ffh = gelu(x @ Wff1^T + bff1)
    k_mgemm<1,false,false><<<dim3(512,4), blk, 0, stream>>>(
        3, nullptr, 12, -1, bff1 + l*512, nullptr, 6, 0, 512, 128, 128);
    // y = ffh @ Wff2^T + bff2
    k_mgemm<0,false,false><<<dim3(512,1), blk, 0, stream>>>(
        6, nullptr, 13, -1, bff2 + l*128, nullptr, 4, 0, 128, 512, 512);
    k_add_ln<<<CBL/4, blk, 0, stream>>>(ln2_g + l*128, ln2_b + l*128);
  }

  k_copy_out<<<(CBS*CH)/256, blk, 0, stream>>>(out);
}